// Round 3
// baseline (477.098 us; speedup 1.0000x reference)
//
#include <hip/hip_runtime.h>
#include <hip/hip_bf16.h>
#include <stdint.h>
#include <stddef.h>

typedef _Float16 f16;
typedef __attribute__((ext_vector_type(8))) _Float16 f16x8;
typedef __attribute__((ext_vector_type(4))) _Float16 f16x4;
typedef __attribute__((ext_vector_type(4))) float f32x4;
typedef __attribute__((ext_vector_type(16))) float f32x16;

#define MFMA_F16(a, b, c) __builtin_amdgcn_mfma_f32_16x16x32_f16(a, b, c, 0, 0, 0)
#define MFMA32_F16(a, b, c) __builtin_amdgcn_mfma_f32_32x32x16_f16(a, b, c, 0, 0, 0)

__device__ __forceinline__ uint32_t swz(uint32_t ci) {
    return (ci & ~7u) | ((ci ^ (ci >> 3)) & 7u);
}

__device__ __forceinline__ void async_ld16(void* lds, const void* g) {
    __builtin_amdgcn_global_load_lds(
        (const __attribute__((address_space(1))) void*)g,
        (__attribute__((address_space(3))) void*)lds, 16, 0, 0);
}

// ---------------------------------------------------------------- transpose W
__global__ __launch_bounds__(256) void k_transpose_cast(
        const float* __restrict__ S, f16* __restrict__ D, int rows, int cols) {
    __shared__ float tile[32][33];
    int x = threadIdx.x & 31, y = threadIdx.x >> 5;
    int c0 = blockIdx.x * 32, r0 = blockIdx.y * 32;
#pragma unroll
    for (int i = 0; i < 32; i += 8)
        tile[y + i][x] = S[(size_t)(r0 + y + i) * cols + c0 + x];
    __syncthreads();
#pragma unroll
    for (int i = 0; i < 32; i += 8)
        D[(size_t)(c0 + y + i) * rows + r0 + x] = (f16)tile[x][y + i];
}

// ---------------------------------------------------------------- RMSNorm
__global__ __launch_bounds__(256) void k_rmsnorm(
        const float* __restrict__ seq, const float* __restrict__ w, f16* __restrict__ X) {
    int row = blockIdx.x, t = threadIdx.x;
    const float4* sp = (const float4*)(seq + (size_t)row * 1024);
    float4 v = sp[t];
    float ss = v.x * v.x + v.y * v.y + v.z * v.z + v.w * v.w;
#pragma unroll
    for (int off = 32; off >= 1; off >>= 1) ss += __shfl_xor(ss, off, 64);
    __shared__ float red[4];
    if ((t & 63) == 0) red[t >> 6] = ss;
    __syncthreads();
    float tot = red[0] + red[1] + red[2] + red[3];
    float rs = rsqrtf(tot * (1.0f / 1024.0f) + 1.1920929e-07f);
    const float4* wp = (const float4*)w;
    float4 wv = wp[t];
    f16x4 o;
    o[0] = (f16)(v.x * rs * wv.x);
    o[1] = (f16)(v.y * rs * wv.y);
    o[2] = (f16)(v.z * rs * wv.z);
    o[3] = (f16)(v.w * rs * wv.w);
    *(f16x4*)(X + (size_t)row * 1024 + t * 4) = o;
}

// ---------------------------------------------------------------- GEMM
// C[M x N] = A[M x K] @ BT[N x K]^T.  128x128 tile, BK=32, 4 waves of 64x64,
// 32x32x16 MFMA with operand-swapped (transposed) accumulator:
//   lane&31 = C-row within 32-block, reg = (q*4+r) -> C-col = 8q + 4*(lane>>5) + r
template <bool OUTF32>
__global__ __launch_bounds__(256) void k_gemm(
        const f16* __restrict__ A, const f16* __restrict__ BT,
        void* __restrict__ Cv, int M, int N, int K) {
    __shared__ f16 As[128 * 32];
    __shared__ f16 Bs[128 * 32];
    const int t = threadIdx.x;
    const int lane = t & 63, wave = t >> 6, l32 = lane & 31, half = lane >> 5;
    const int m0 = blockIdx.y * 128, n0 = blockIdx.x * 128;
    const int wm = (wave & 1) * 64, wn = (wave >> 1) * 64;
    f32x16 acc[2][2];
#pragma unroll
    for (int i = 0; i < 2; i++)
#pragma unroll
        for (int j = 0; j < 2; j++)
#pragma unroll
            for (int r = 0; r < 16; r++) acc[i][j][r] = 0.f;

    uint32_t aoff[2][2], boff[2][2];   // [block][k-step]
#pragma unroll
    for (int bk = 0; bk < 2; bk++)
#pragma unroll
        for (int ks = 0; ks < 2; ks++) {
            aoff[bk][ks] = swz((uint32_t)(wm + bk * 32 + l32) * 4 + ks * 2 + half) * 16;
            boff[bk][ks] = swz((uint32_t)(wn + bk * 32 + l32) * 4 + ks * 2 + half) * 16;
        }
    uint32_t c0 = swz(t), c1 = swz(t + 256);
    const f16* Ag0 = A + (size_t)(m0 + (c0 >> 2)) * K + (c0 & 3) * 8;
    const f16* Ag1 = A + (size_t)(m0 + (c1 >> 2)) * K + (c1 & 3) * 8;
    const f16* Bg0 = BT + (size_t)(n0 + (c0 >> 2)) * K + (c0 & 3) * 8;
    const f16* Bg1 = BT + (size_t)(n0 + (c1 >> 2)) * K + (c1 & 3) * 8;
    char* AsB = (char*)As;
    char* BsB = (char*)Bs;

    for (int k0 = 0; k0 < K; k0 += 32) {
        __syncthreads();
        async_ld16(AsB + t * 16, Ag0 + k0);
        async_ld16(AsB + (t + 256) * 16, Ag1 + k0);
        async_ld16(BsB + t * 16, Bg0 + k0);
        async_ld16(BsB + (t + 256) * 16, Bg1 + k0);
        __builtin_amdgcn_s_waitcnt(0x0f70);  // vmcnt(0)
        __syncthreads();
        f16x8 a[2][2], b[2][2];
#pragma unroll
        for (int bk = 0; bk < 2; bk++)
#pragma unroll
            for (int ks = 0; ks < 2; ks++) {
                a[bk][ks] = *(const f16x8*)(AsB + aoff[bk][ks]);
                b[bk][ks] = *(const f16x8*)(BsB + boff[bk][ks]);
            }
#pragma unroll
        for (int mb = 0; mb < 2; mb++)
#pragma unroll
            for (int nb = 0; nb < 2; nb++) {
                // operand-swapped: D^T -> lane&31 = m-row, regs = n-col
                acc[mb][nb] = MFMA32_F16(b[nb][0], a[mb][0], acc[mb][nb]);
                acc[mb][nb] = MFMA32_F16(b[nb][1], a[mb][1], acc[mb][nb]);
            }
    }
#pragma unroll
    for (int mb = 0; mb < 2; mb++) {
        int row = m0 + wm + mb * 32 + l32;
#pragma unroll
        for (int nb = 0; nb < 2; nb++) {
            int colb = n0 + wn + nb * 32 + half * 4;
#pragma unroll
            for (int q = 0; q < 4; q++) {
                int col = colb + q * 8;
                if (OUTF32) {
                    f32x4 ov;
#pragma unroll
                    for (int r = 0; r < 4; r++) ov[r] = acc[mb][nb][q * 4 + r];
                    *(f32x4*)((float*)Cv + (size_t)row * N + col) = ov;
                } else {
                    f16x4 ov;
#pragma unroll
                    for (int r = 0; r < 4; r++) ov[r] = (f16)acc[mb][nb][q * 4 + r];
                    *(f16x4*)((f16*)Cv + (size_t)row * N + col) = ov;
                }
            }
        }
    }
}

// ---------------------------------------------------------------- fused prep
__global__ __launch_bounds__(256) void k_prep(
        const f16* __restrict__ qkv, const float* __restrict__ pm,
        f16* __restrict__ Q, f16* __restrict__ Kb, f16* __restrict__ Vt) {
    const int jt = blockIdx.x, wh = blockIdx.y;
    const int bw = wh >> 4, h = wh & 15;
    const int t = threadIdx.x;
    const int g = t & 15;

    // ---- RoPE for q,k of 64 tokens
#pragma unroll
    for (int it = 0; it < 4; it++) {
        int i = jt * 64 + it * 16 + (t >> 4);
        int tok = bw * 512 + i;
        int n = tok & 8191;
        const f16* qp = qkv + (size_t)tok * 3072 + h * 64 + g * 4;
        f16x4 qv = *(const f16x4*)(qp);
        f16x4 kv = *(const f16x4*)(qp + 1024);
        float q0 = qv[0], q1 = qv[1], q2 = qv[2], q3 = qv[3];
        float k0 = kv[0], k1 = kv[1], k2 = kv[2], k3 = kv[3];
        float fn = (float)n;
        float a0 = fn * exp2f(-0.41524101186092025f * (float)(2 * g));
        float a1 = fn * exp2f(-0.41524101186092025f * (float)(2 * g + 1));
        float s0, c0, s1, c1;
        sincosf(a0, &s0, &c0);
        sincosf(a1, &s1, &c1);
        f16x4 qo, ko;
        qo[0] = (f16)(q0 * c0 - q1 * s0);
        qo[1] = (f16)(q1 * c0 + q0 * s0);
        qo[2] = (f16)(q2 * c1 - q3 * s1);
        qo[3] = (f16)(q3 * c1 + q2 * s1);
        ko[0] = (f16)(k0 * c0 - k1 * s0);
        ko[1] = (f16)(k1 * c0 + k0 * s0);
        ko[2] = (f16)(k2 * c1 - k3 * s1);
        ko[3] = (f16)(k3 * c1 + k2 * s1);
        *(f16x4*)(Q + ((size_t)wh * 512 + i) * 64 + g * 4) = qo;
        *(f16x4*)(Kb + ((size_t)wh * 576 + 16 + i) * 64 + g * 4) = ko;
    }

    // ---- V transpose
    __shared__ f16 tile[64][72];
    {
        int jr = t >> 2, cq = (t & 3) * 16;
        const f16* src = qkv + ((size_t)(bw * 512 + jt * 64 + jr)) * 3072 + 2048 + h * 64 + cq;
        *(f16x8*)(&tile[jr][cq]) = *(const f16x8*)(src);
        *(f16x8*)(&tile[jr][cq + 8]) = *(const f16x8*)(src + 8);
        __syncthreads();
        int d = t >> 2, jq = (t & 3) * 16;
        f16* dst = Vt + ((size_t)wh * 64 + d) * 576 + 16 + jt * 64 + jq;
        f16x8 o0, o1;
#pragma unroll
        for (int jj = 0; jj < 8; jj++) o0[jj] = tile[jq + jj][d];
#pragma unroll
        for (int jj = 0; jj < 8; jj++) o1[jj] = tile[jq + 8 + jj][d];
        *(f16x8*)(dst) = o0;
        *(f16x8*)(dst + 8) = o1;
    }

    if (jt == 0) {
        const float* pk = pm + (size_t)h * 1024;
        f16* kb = Kb + (size_t)wh * 36864;
        int e0 = t * 4;
#pragma unroll
        for (int k = 0; k < 4; k++) kb[e0 + k] = (f16)pk[e0 + k];
        const float* pv = pm + 16384 + (size_t)h * 1024;
        f16* vb = Vt + (size_t)wh * 36864;
        int d = t & 63, s4 = (t >> 6) * 4;
#pragma unroll
        for (int k = 0; k < 4; k++)
            vb[(size_t)d * 576 + s4 + k] = (f16)pv[(s4 + k) * 64 + d];
    } else if (jt == 1) {
        f16* kb = Kb + (size_t)wh * 36864;
#pragma unroll
        for (int k = 0; k < 12; k++) kb[33792 + t + k * 256] = (f16)0.f;
        f16* vb = Vt + (size_t)wh * 36864;
        int d = t >> 2, rep = t & 3;
#pragma unroll
        for (int m = 0; m < 12; m++)
            vb[(size_t)d * 576 + 528 + rep * 12 + m] = (f16)0.f;
    }
}

// ---------------------------------------------------------------- attention
__global__ __launch_bounds__(256) void k_attn(
        const f16* __restrict__ Q, const f16* __restrict__ Kb,
        const f16* __restrict__ Vt, f16* __restrict__ AO) {
    const int qt = blockIdx.x, wh = blockIdx.y;
    const int i0 = qt * 64;
    const int t = threadIdx.x, lane = t & 63, wave = t >> 6, quad = lane >> 4, l16 = lane & 15;
    __shared__ f16 Ks[64 * 64];
    __shared__ f16 Vs[64 * 64];
    __shared__ f16 Ps[4][16][80];

    const int ig = i0 + wave * 16 + l16;
    const f16* qptr = Q + ((size_t)wh * 512 + ig) * 64 + quad * 8;
    f16x8 qf0 = *(const f16x8*)(qptr);
    f16x8 qf1 = *(const f16x8*)(qptr + 32);

    const f32x4 zero = {0.f, 0.f, 0.f, 0.f};
    f32x4 o[4];
#pragma unroll
    for (int i = 0; i < 4; i++) o[i] = zero;
    float m_l = -1e30f, l_l = 0.f;

    uint32_t c0 = swz(t), c1 = swz(t + 256);
    const f16* kg0 = Kb + ((size_t)wh * 576 + (c0 >> 3)) * 64 + (c0 & 7) * 8;
    const f16* kg1 = Kb + ((size_t)wh * 576 + (c1 >> 3)) * 64 + (c1 & 7) * 8;
    const f16* vg0 = Vt + ((size_t)wh * 64 + (c0 >> 3)) * 576 + (c0 & 7) * 8;
    const f16* vg1 = Vt + ((size_t)wh * 64 + (c1 >> 3)) * 576 + (c1 & 7) * 8;
    char* KsB = (char*)Ks;
    char* VsB = (char*)Vs;

    uint32_t boff[4][2];
#pragma unroll
    for (int i = 0; i < 4; i++)
#pragma unroll
        for (int f = 0; f < 2; f++)
            boff[i][f] = swz((uint32_t)(i * 16 + l16) * 8 + f * 4 + quad) * 16;

    f16* psrow = &Ps[wave][l16][0];
    const int njt = (qt + 2 < 9) ? (qt + 2) : 9;

    for (int jt = 0; jt < njt; jt++) {
        const int j0 = jt * 64;
        __syncthreads();
        async_ld16(KsB + t * 16, kg0 + (size_t)j0 * 64);
        async_ld16(KsB + (t + 256) * 16, kg1 + (size_t)j0 * 64);
        async_ld16(VsB + t * 16, vg0 + j0);
        async_ld16(VsB + (t + 256) * 16, vg1 + j0);
        __builtin_amdgcn_s_waitcnt(0x0f70);  // vmcnt(0)
        __syncthreads();

        f32x4 s[4];
#pragma unroll
        for (int jb = 0; jb < 4; jb++) {
            f16x8 kv0 = *(const f16x8*)(KsB + boff[jb][0]);
            f16x8 kv1 = *(const f16x8*)(KsB + boff[jb][1]);
            f32x4 z = zero;
            z = MFMA_F16(kv0, qf0, z);
            z = MFMA_F16(kv1, qf1, z);
            s[jb] = z;
        }
        float mx = -1e30f;
#pragma unroll
        for (int jb = 0; jb < 4; jb++)
#pragma unroll
            for (int r = 0; r < 4; r++) {
                int jg = j0 + jb * 16 + quad * 4 + r;
                bool ok = (jg <= ig + 16) && (jg < 528);
                float val = ok ? s[jb][r] * 0.125f : -1e30f;
                s[jb][r] = val;
                mx = fmaxf(mx, val);
            }
        mx = fmaxf(mx, __shfl_xor(mx, 16, 64));
        mx = fmaxf(mx, __shfl_xor(mx, 32, 64));
        float mnew = fmaxf(m_l, mx);
        float alpha = __expf(m_l - mnew);
        m_l = mnew;
        float rsum = 0.f;
#pragma unroll
        for (int jb = 0; jb < 4; jb++) {
            f16x4 pw;
#pragma unroll
            for (int r = 0; r < 4; r++) {
                float p = __expf(s[jb][r] - mnew);
                rsum += p;
                pw[r] = (f16)p;
            }
            *(f16x4*)(psrow + jb * 16 + quad * 4) = pw;
        }
        rsum += __shfl_xor(rsum, 16, 64);
        rsum += __shfl_xor(rsum, 32, 64);
        l_l = l_l * alpha + rsum;
#pragma unroll
        for (int nd = 0; nd < 4; nd++) o[nd] *= alpha;
        __syncthreads();

        f16x8 pb0 = *(const f16x8*)(psrow + quad * 8);
        f16x8 pb1 = *(const f16x8*)(psrow + 32 + quad * 8);
#pragma unroll
        for (int nd = 0; nd < 4; nd++) {
            f16x8 v0 = *(const f16x8*)(VsB + boff[nd][0]);
            f16x8 v1 = *(const f16x8*)(VsB + boff[nd][1]);
            o[nd] = MFMA_F16(v0, pb0, o[nd]);
            o[nd] = MFMA_F16(v1, pb1, o[nd]);
        }
    }

    const int bw = wh >> 4, h = wh & 15;
    float inv = 1.f / l_l;
    f16* dst = AO + ((size_t)bw * 512 + ig) * 1024 + h * 64 + quad * 4;
#pragma unroll
    for (int nd = 0; nd < 4; nd++) {
        f16x4 ov;
#pragma unroll
        for (int r = 0; r < 4; r++) ov[r] = (f16)(o[nd][r] * inv);
        *(f16x4*)(dst + nd * 16) = ov;
    }
}

// ---------------------------------------------------------------- launch
extern "C" void kernel_launch(void* const* d_in, const int* in_sizes, int n_in,
                              void* d_out, int out_size, void* d_ws, size_t ws_size,
                              hipStream_t stream) {
    const float* seq   = (const float*)d_in[0];
    const float* wnorm = (const float*)d_in[1];
    const float* Wqkv  = (const float*)d_in[2];
    const float* Wout  = (const float*)d_in[3];
    const float* pm    = (const float*)d_in[4];
    float* out = (float*)d_out;
    char* ws = (char*)d_ws;

    f16* WqkvT = (f16*)(ws + 0);            // 3072x1024        = 6 MB
    f16* WoutT = (f16*)(ws + 6291456);      // 1024x1024        = 2 MB
    f16* X     = (f16*)(ws + 8388608);      // 16384x1024       = 32 MB (aliased with Q)
    f16* Qb    = X;
    f16* qkv   = (f16*)(ws + 41943040);     // 16384x3072       = 96 MB (aliased with AO)
    f16* AO    = qkv;
    f16* Kb    = (f16*)(ws + 142606336);    // 512x576x64       = 36 MB
    f16* Vt    = (f16*)(ws + 180355072);    // 512x64x576       = 36 MB

    k_transpose_cast<<<dim3(96, 32), 256, 0, stream>>>(Wqkv, WqkvT, 1024, 3072);
    k_transpose_cast<<<dim3(32, 32), 256, 0, stream>>>(Wout, WoutT, 1024, 1024);
    k_rmsnorm<<<16384, 256, 0, stream>>>(seq, wnorm, X);
    k_gemm<false><<<dim3(24, 128), 256, 0, stream>>>(X, WqkvT, qkv, 16384, 3072, 1024);
    k_prep<<<dim3(8, 512), 256, 0, stream>>>(qkv, pm, Qb, Kb, Vt);
    k_attn<<<dim3(8, 512), 256, 0, stream>>>(Qb, Kb, Vt, AO);
    k_gemm<true><<<dim3(8, 128), 256, 0, stream>>>(AO, WoutT, out, 16384, 1024, 1024);
}

// Round 5
// 434.258 us; speedup vs baseline: 1.0987x; 1.0987x over previous
//
#include <hip/hip_runtime.h>
#include <hip/hip_bf16.h>
#include <stdint.h>
#include <stddef.h>

typedef _Float16 f16;
typedef __attribute__((ext_vector_type(8))) _Float16 f16x8;
typedef __attribute__((ext_vector_type(4))) _Float16 f16x4;
typedef __attribute__((ext_vector_type(4))) float f32x4;
typedef __attribute__((ext_vector_type(16))) float f32x16;

#define MFMA_F16(a, b, c) __builtin_amdgcn_mfma_f32_16x16x32_f16(a, b, c, 0, 0, 0)
#define MFMA32_F16(a, b, c) __builtin_amdgcn_mfma_f32_32x32x16_f16(a, b, c, 0, 0, 0)

#define LOG2_10K_32 0.41524101186092025f   // log2(10000)/32

__device__ __forceinline__ uint32_t swz(uint32_t ci) {
    return (ci & ~7u) | ((ci ^ (ci >> 3)) & 7u);
}

__device__ __forceinline__ void async_ld16(void* lds, const void* g) {
    __builtin_amdgcn_global_load_lds(
        (const __attribute__((address_space(1))) void*)g,
        (__attribute__((address_space(3))) void*)lds, 16, 0, 0);
}

// ---------------------------------------------------------------- transpose W
__global__ __launch_bounds__(256) void k_transpose_cast(
        const float* __restrict__ S, f16* __restrict__ D, int rows, int cols) {
    __shared__ float tile[32][33];
    int x = threadIdx.x & 31, y = threadIdx.x >> 5;
    int c0 = blockIdx.x * 32, r0 = blockIdx.y * 32;
#pragma unroll
    for (int i = 0; i < 32; i += 8)
        tile[y + i][x] = S[(size_t)(r0 + y + i) * cols + c0 + x];
    __syncthreads();
#pragma unroll
    for (int i = 0; i < 32; i += 8)
        D[(size_t)(c0 + y + i) * rows + r0 + x] = (f16)tile[x][y + i];
}

// ---------------------------------------------------------------- RMSNorm
__global__ __launch_bounds__(256) void k_rmsnorm(
        const float* __restrict__ seq, const float* __restrict__ w, f16* __restrict__ X) {
    int row = blockIdx.x, t = threadIdx.x;
    const float4* sp = (const float4*)(seq + (size_t)row * 1024);
    float4 v = sp[t];
    float ss = v.x * v.x + v.y * v.y + v.z * v.z + v.w * v.w;
#pragma unroll
    for (int off = 32; off >= 1; off >>= 1) ss += __shfl_xor(ss, off, 64);
    __shared__ float red[4];
    if ((t & 63) == 0) red[t >> 6] = ss;
    __syncthreads();
    float tot = red[0] + red[1] + red[2] + red[3];
    float rs = rsqrtf(tot * (1.0f / 1024.0f) + 1.1920929e-07f);
    const float4* wp = (const float4*)w;
    float4 wv = wp[t];
    f16x4 o;
    o[0] = (f16)(v.x * rs * wv.x);
    o[1] = (f16)(v.y * rs * wv.y);
    o[2] = (f16)(v.z * rs * wv.z);
    o[3] = (f16)(v.w * rs * wv.w);
    *(f16x4*)(X + (size_t)row * 1024 + t * 4) = o;
}

// ---------------------------------------------------------------- QKV GEMM (fused RoPE + scatter)
// EXPERIMENT r5: pre-round acc to f16 before RoPE so Q/K/V bits exactly match
// the r3 (gemm -> f16 qkv -> prep) pipeline. Isolates rounding-path vs
// addressing as the cause of r4's absmax 3.1e-2.
__global__ __launch_bounds__(256) void k_gemm_qkv(
        const f16* __restrict__ A, const f16* __restrict__ BT,
        f16* __restrict__ Qb, f16* __restrict__ Kb, f16* __restrict__ Vt) {
    const int K = 1024;
    __shared__ f16 As[128 * 32];
    __shared__ f16 Bs[128 * 32];
    const int t = threadIdx.x;
    const int lane = t & 63, wave = t >> 6, l32 = lane & 31, half = lane >> 5;
    const int m0 = blockIdx.y * 128, n0 = blockIdx.x * 128;
    const int wm = (wave & 1) * 64, wn = (wave >> 1) * 64;
    f32x16 acc[2][2];
#pragma unroll
    for (int i = 0; i < 2; i++)
#pragma unroll
        for (int j = 0; j < 2; j++)
#pragma unroll
            for (int r = 0; r < 16; r++) acc[i][j][r] = 0.f;

    uint32_t aoff[2][2], boff[2][2];
#pragma unroll
    for (int bk = 0; bk < 2; bk++)
#pragma unroll
        for (int ks = 0; ks < 2; ks++) {
            aoff[bk][ks] = swz((uint32_t)(wm + bk * 32 + l32) * 4 + ks * 2 + half) * 16;
            boff[bk][ks] = swz((uint32_t)(wn + bk * 32 + l32) * 4 + ks * 2 + half) * 16;
        }
    uint32_t c0 = swz(t), c1 = swz(t + 256);
    const f16* Ag0 = A + (size_t)(m0 + (c0 >> 2)) * K + (c0 & 3) * 8;
    const f16* Ag1 = A + (size_t)(m0 + (c1 >> 2)) * K + (c1 & 3) * 8;
    const f16* Bg0 = BT + (size_t)(n0 + (c0 >> 2)) * K + (c0 & 3) * 8;
    const f16* Bg1 = BT + (size_t)(n0 + (c1 >> 2)) * K + (c1 & 3) * 8;
    char* AsB = (char*)As;
    char* BsB = (char*)Bs;

    for (int k0 = 0; k0 < K; k0 += 32) {
        __syncthreads();
        async_ld16(AsB + t * 16, Ag0 + k0);
        async_ld16(AsB + (t + 256) * 16, Ag1 + k0);
        async_ld16(BsB + t * 16, Bg0 + k0);
        async_ld16(BsB + (t + 256) * 16, Bg1 + k0);
        __builtin_amdgcn_s_waitcnt(0x0f70);  // vmcnt(0)
        __syncthreads();
        f16x8 a[2][2], b[2][2];
#pragma unroll
        for (int bk = 0; bk < 2; bk++)
#pragma unroll
            for (int ks = 0; ks < 2; ks++) {
                a[bk][ks] = *(const f16x8*)(AsB + aoff[bk][ks]);
                b[bk][ks] = *(const f16x8*)(BsB + boff[bk][ks]);
            }
#pragma unroll
        for (int mb = 0; mb < 2; mb++)
#pragma unroll
            for (int nb = 0; nb < 2; nb++) {
                acc[mb][nb] = MFMA32_F16(b[nb][0], a[mb][0], acc[mb][nb]);
                acc[mb][nb] = MFMA32_F16(b[nb][1], a[mb][1], acc[mb][nb]);
            }
    }

    // region uniform per block: 0=Q, 1=K, 2=V
    const int region = n0 >> 10;
#pragma unroll
    for (int mb = 0; mb < 2; mb++) {
        int row = m0 + wm + mb * 32 + l32;       // token 0..16383
        int b_ = row >> 13, n_ = row & 8191;
        int win = n_ >> 9, i_ = n_ & 511;
        float fn = (float)n_;
#pragma unroll
        for (int nb = 0; nb < 2; nb++) {
            int colb = n0 + wn + nb * 32 + half * 4;
            int cr = colb & 1023;                 // feature idx within region
            int h = cr >> 6;
            int d0 = cr & 63;                     // multiple of 4
            int wh = ((b_ * 16 + win) << 4) + h;
            if (region < 2) {
                f16* base = (region == 0)
                    ? (Qb + ((size_t)wh * 512 + i_) * 64)
                    : (Kb + ((size_t)wh * 576 + 16 + i_) * 64);
#pragma unroll
                for (int q = 0; q < 4; q++) {
                    int d = d0 + q * 8;
                    float j0f = (float)(d >> 1);
                    float ang0 = fn * exp2f(-LOG2_10K_32 * j0f);
                    float ang1 = fn * exp2f(-LOG2_10K_32 * (j0f + 1.0f));
                    float s0, c0f, s1, c1f;
                    sincosf(ang0, &s0, &c0f);
                    sincosf(ang1, &s1, &c1f);
                    // r3-identical numerics: round acc to f16 BEFORE rotation
                    float x0 = (float)(f16)acc[mb][nb][q * 4 + 0];
                    float x1 = (float)(f16)acc[mb][nb][q * 4 + 1];
                    float x2 = (float)(f16)acc[mb][nb][q * 4 + 2];
                    float x3 = (float)(f16)acc[mb][nb][q * 4 + 3];
                    f16x4 ov;
                    ov[0] = (f16)(x0 * c0f - x1 * s0);
                    ov[1] = (f16)(x1 * c0f + x0 * s0);
                    ov[2] = (f16)(x2 * c1f - x3 * s1);
                    ov[3] = (f16)(x3 * c1f + x2 * s1);
                    *(f16x4*)(base + d) = ov;
                }
            } else {
                f16* vbase = Vt + (size_t)wh * 36864 + 16 + i_;
#pragma unroll
                for (int q = 0; q < 4; q++)
#pragma unroll
                    for (int r = 0; r < 4; r++)
                        vbase[(size_t)(d0 + q * 8 + r) * 576] = (f16)acc[mb][nb][q * 4 + r];
            }
        }
    }
}

// ---------------------------------------------------------------- out GEMM
__global__ __launch_bounds__(256) void k_gemm_out(
        const f16* __restrict__ A, const f16* __restrict__ BT,
        float* __restrict__ C, int M, int N, int K) {
    __shared__ f16 As[128 * 32];
    __shared__ f16 Bs[128 * 32];
    const int t = threadIdx.x;
    const int lane = t & 63, wave = t >> 6, l32 = lane & 31, half = lane >> 5;
    const int m0 = blockIdx.y * 128, n0 = blockIdx.x * 128;
    const int wm = (wave & 1) * 64, wn = (wave >> 1) * 64;
    f32x16 acc[2][2];
#pragma unroll
    for (int i = 0; i < 2; i++)
#pragma unroll
        for (int j = 0; j < 2; j++)
#pragma unroll
            for (int r = 0; r < 16; r++) acc[i][j][r] = 0.f;

    uint32_t aoff[2][2], boff[2][2];
#pragma unroll
    for (int bk = 0; bk < 2; bk++)
#pragma unroll
        for (int ks = 0; ks < 2; ks++) {
            aoff[bk][ks] = swz((uint32_t)(wm + bk * 32 + l32) * 4 + ks * 2 + half) * 16;
            boff[bk][ks] = swz((uint32_t)(wn + bk * 32 + l32) * 4 + ks * 2 + half) * 16;
        }
    uint32_t c0 = swz(t), c1 = swz(t + 256);
    const f16* Ag0 = A + (size_t)(m0 + (c0 >> 2)) * K + (c0 & 3) * 8;
    const f16* Ag1 = A + (size_t)(m0 + (c1 >> 2)) * K + (c1 & 3) * 8;
    const f16* Bg0 = BT + (size_t)(n0 + (c0 >> 2)) * K + (c0 & 3) * 8;
    const f16* Bg1 = BT + (size_t)(n0 + (c1 >> 2)) * K + (c1 & 3) * 8;
    char* AsB = (char*)As;
    char* BsB = (char*)Bs;

    for (int k0 = 0; k0 < K; k0 += 32) {
        __syncthreads();
        async_ld16(AsB + t * 16, Ag0 + k0);
        async_ld16(AsB + (t + 256) * 16, Ag1 + k0);
        async_ld16(BsB + t * 16, Bg0 + k0);
        async_ld16(BsB + (t + 256) * 16, Bg1 + k0);
        __builtin_amdgcn_s_waitcnt(0x0f70);  // vmcnt(0)
        __syncthreads();
        f16x8 a[2][2], b[2][2];
#pragma unroll
        for (int bk = 0; bk < 2; bk++)
#pragma unroll
            for (int ks = 0; ks < 2; ks++) {
                a[bk][ks] = *(const f16x8*)(AsB + aoff[bk][ks]);
                b[bk][ks] = *(const f16x8*)(BsB + boff[bk][ks]);
            }
#pragma unroll
        for (int mb = 0; mb < 2; mb++)
#pragma unroll
            for (int nb = 0; nb < 2; nb++) {
                acc[mb][nb] = MFMA32_F16(b[nb][0], a[mb][0], acc[mb][nb]);
                acc[mb][nb] = MFMA32_F16(b[nb][1], a[mb][1], acc[mb][nb]);
            }
    }
#pragma unroll
    for (int mb = 0; mb < 2; mb++) {
        int row = m0 + wm + mb * 32 + l32;
#pragma unroll
        for (int nb = 0; nb < 2; nb++) {
            int colb = n0 + wn + nb * 32 + half * 4;
#pragma unroll
            for (int q = 0; q < 4; q++) {
                f32x4 ov;
#pragma unroll
                for (int r = 0; r < 4; r++) ov[r] = acc[mb][nb][q * 4 + r];
                *(f32x4*)(C + (size_t)row * N + colb + q * 8) = ov;
            }
        }
    }
}

// ---------------------------------------------------------------- pm fill + pads
__global__ __launch_bounds__(256) void k_pmpad(
        const float* __restrict__ pm, f16* __restrict__ Kb, f16* __restrict__ Vt) {
    int wh = blockIdx.x, h = wh & 15, t = threadIdx.x;
    const float* pk = pm + (size_t)h * 1024;
    f16* kb = Kb + (size_t)wh * 36864;
    int e0 = t * 4;
#pragma unroll
    for (int k = 0; k < 4; k++) kb[e0 + k] = (f16)pk[e0 + k];
#pragma unroll
    for (int k = 0; k < 12; k++) kb[33792 + t + k * 256] = (f16)0.f;
    const float* pv = pm + 16384 + (size_t)h * 1024;
    f16* vb = Vt + (size_t)wh * 36864;
    {
        int d = t & 63, s4 = (t >> 6) * 4;
#pragma unroll
        for (int k = 0; k < 4; k++)
            vb[(size_t)d * 576 + s4 + k] = (f16)pv[(s4 + k) * 64 + d];
    }
    {
        int d = t >> 2, rep = t & 3;
#pragma unroll
        for (int m = 0; m < 12; m++)
            vb[(size_t)d * 576 + 528 + rep * 12 + m] = (f16)0.f;
    }
}

// ---------------------------------------------------------------- attention
__global__ __launch_bounds__(256) void k_attn(
        const f16* __restrict__ Q, const f16* __restrict__ Kb,
        const f16* __restrict__ Vt, f16* __restrict__ AO) {
    const int qt = blockIdx.x, wh = blockIdx.y;
    const int i0 = qt * 64;
    const int t = threadIdx.x, lane = t & 63, wave = t >> 6, quad = lane >> 4, l16 = lane & 15;
    __shared__ f16 Ks[64 * 64];
    __shared__ f16 Vs[64 * 64];
    __shared__ f16 Ps[4][16][80];

    const int ig = i0 + wave * 16 + l16;
    const f16* qptr = Q + ((size_t)wh * 512 + ig) * 64 + quad * 8;
    f16x8 qf0 = *(const f16x8*)(qptr);
    f16x8 qf1 = *(const f16x8*)(qptr + 32);

    const f32x4 zero = {0.f, 0.f, 0.f, 0.f};
    f32x4 o[4];
#pragma unroll
    for (int i = 0; i < 4; i++) o[i] = zero;
    float m_l = -1e30f, l_l = 0.f;

    uint32_t c0 = swz(t), c1 = swz(t + 256);
    const f16* kg0 = Kb + ((size_t)wh * 576 + (c0 >> 3)) * 64 + (c0 & 7) * 8;
    const f16* kg1 = Kb + ((size_t)wh * 576 + (c1 >> 3)) * 64 + (c1 & 7) * 8;
    const f16* vg0 = Vt + ((size_t)wh * 64 + (c0 >> 3)) * 576 + (c0 & 7) * 8;
    const f16* vg1 = Vt + ((size_t)wh * 64 + (c1 >> 3)) * 576 + (c1 & 7) * 8;
    char* KsB = (char*)Ks;
    char* VsB = (char*)Vs;

    uint32_t boff[4][2];
#pragma unroll
    for (int i = 0; i < 4; i++)
#pragma unroll
        for (int f = 0; f < 2; f++)
            boff[i][f] = swz((uint32_t)(i * 16 + l16) * 8 + f * 4 + quad) * 16;

    f16* psrow = &Ps[wave][l16][0];
    const int njt = (qt + 2 < 9) ? (qt + 2) : 9;

    for (int jt = 0; jt < njt; jt++) {
        const int j0 = jt * 64;
        __syncthreads();
        async_ld16(KsB + t * 16, kg0 + (size_t)j0 * 64);
        async_ld16(KsB + (t + 256) * 16, kg1 + (size_t)j0 * 64);
        async_ld16(VsB + t * 16, vg0 + j0);
        async_ld16(VsB + (t + 256) * 16, vg1 + j0);
        __builtin_amdgcn_s_waitcnt(0x0f70);  // vmcnt(0)
        __syncthreads();

        f32x4 s[4];
#pragma unroll
        for (int jb = 0; jb < 4; jb++) {
            f16x8 kv0 = *(const f16x8*)(KsB + boff[jb][0]);
            f16x8 kv1 = *(const f16x8*)(KsB + boff[jb][1]);
            f32x4 z = zero;
            z = MFMA_F16(kv0, qf0, z);
            z = MFMA_F16(kv1, qf1, z);
            s[jb] = z;
        }
        float mx = -1e30f;
#pragma unroll
        for (int jb = 0; jb < 4; jb++)
#pragma unroll
            for (int r = 0; r < 4; r++) {
                int jg = j0 + jb * 16 + quad * 4 + r;
                bool ok = (jg <= ig + 16) && (jg < 528);
                float val = ok ? s[jb][r] * 0.125f : -1e30f;
                s[jb][r] = val;
                mx = fmaxf(mx, val);
            }
        mx = fmaxf(mx, __shfl_xor(mx, 16, 64));
        mx = fmaxf(mx, __shfl_xor(mx, 32, 64));
        float mnew = fmaxf(m_l, mx);
        float alpha = __expf(m_l - mnew);
        m_l = mnew;
        float rsum = 0.f;
#pragma unroll
        for (int jb = 0; jb < 4; jb++) {
            f16x4 pw;
#pragma unroll
            for (int r = 0; r < 4; r++) {
                float p = __expf(s[jb][r] - mnew);
                rsum += p;
                pw[r] = (f16)p;
            }
            *(f16x4*)(psrow + jb * 16 + quad * 4) = pw;
        }
        rsum += __shfl_xor(rsum, 16, 64);
        rsum += __shfl_xor(rsum, 32, 64);
        l_l = l_l * alpha + rsum;
#pragma unroll
        for (int nd = 0; nd < 4; nd++) o[nd] *= alpha;
        __syncthreads();

        f16x8 pb0 = *(const f16x8*)(psrow + quad * 8);
        f16x8 pb1 = *(const f16x8*)(psrow + 32 + quad * 8);
#pragma unroll
        for (int nd = 0; nd < 4; nd++) {
            f16x8 v0 = *(const f16x8*)(VsB + boff[nd][0]);
            f16x8 v1 = *(const f16x8*)(VsB + boff[nd][1]);
            o[nd] = MFMA_F16(v0, pb0, o[nd]);
            o[nd] = MFMA_F16(v1, pb1, o[nd]);
        }
    }

    const int bw = wh >> 4, h = wh & 15;
    float inv = 1.f / l_l;
    f16* dst = AO + ((size_t)bw * 512 + ig) * 1024 + h * 64 + quad * 4;
#pragma unroll
    for (int nd = 0; nd < 4; nd++) {
        f16x4 ov;
#pragma unroll
        for (int r = 0; r < 4; r++) ov[r] = (f16)(o[nd][r] * inv);
        *(f16x4*)(dst + nd * 16) = ov;
    }
}

// ---------------------------------------------------------------- launch
extern "C" void kernel_launch(void* const* d_in, const int* in_sizes, int n_in,
                              void* d_out, int out_size, void* d_ws, size_t ws_size,
                              hipStream_t stream) {
    const float* seq   = (const float*)d_in[0];
    const float* wnorm = (const float*)d_in[1];
    const float* Wqkv  = (const float*)d_in[2];
    const float* Wout  = (const float*)d_in[3];
    const float* pm    = (const float*)d_in[4];
    float* out = (float*)d_out;
    char* ws = (char*)d_ws;

    f16* WqkvT = (f16*)(ws + 0);            // 3072x1024  = 6 MB
    f16* WoutT = (f16*)(ws + 6291456);      // 1024x1024  = 2 MB
    f16* X     = (f16*)(ws + 8388608);      // 16384x1024 = 32 MB
    f16* Qb    = (f16*)(ws + 41943040);     // 512x512x64 = 32 MB
    f16* AO    = (f16*)(ws + 75497472);     // 16384x1024 = 32 MB
    f16* Kb    = (f16*)(ws + 109051904);    // 512x576x64 = 36 MB
    f16* Vt    = (f16*)(ws + 146800640);    // 512x64x576 = 36 MB  (end 176 MB)

    k_transpose_cast<<<dim3(96, 32), 256, 0, stream>>>(Wqkv, WqkvT, 1024, 3072);
    k_transpose_cast<<<dim3(32, 32), 256, 0, stream>>>(Wout, WoutT, 1024, 1024);
    k_rmsnorm<<<16384, 256, 0, stream>>>(seq, wnorm, X);
    k_pmpad<<<512, 256, 0, stream>>>(pm, Kb, Vt);
    k_gemm_qkv<<<dim3(24, 128), 256, 0, stream>>>(X, WqkvT, Qb, Kb, Vt);
    k_attn<<<dim3(8, 512), 256, 0, stream>>>(Qb, Kb, Vt, AO);
    k_gemm_out<<<dim3(8, 128), 256, 0, stream>>>(AO, WoutT, out, 16384, 1024, 1024);
}